// Round 2
// baseline (203.792 us; speedup 1.0000x reference)
//
#include <hip/hip_runtime.h>

// B=32, T=512, C=256, F=512.
// Reference softmax is over a size-1 axis -> att == 1.0 exactly, so
// out[b,c,f] = sum_t x[b,t,f], broadcast over c. context/W/b are dead.
// Pure bandwidth: read 33.5 MB (x) + write 16.8 MB (out).
//
// Single fused kernel: 1024 blocks (32 per batch) compute partial column
// sums; the last-arriving block per batch (device-scope atomic counter)
// reduces the 32 L2-hot partials and broadcast-stores the 256 c-rows.

#define BB 32
#define TT 512
#define CC 256
#define FF 512
#define F4 (FF / 4)      // 128 float4 per row
#define TSPLIT 32
#define TROWS (TT / TSPLIT)  // 16 rows per block, 8 per half-block

__device__ __forceinline__ void acc4(float4& a, const float4& v) {
    a.x += v.x; a.y += v.y; a.z += v.z; a.w += v.w;
}

__global__ __launch_bounds__(256) void fused_colsum_bcast(
        const float4* __restrict__ x4,
        float4* __restrict__ part4,     // [B*TSPLIT, F4]
        unsigned* __restrict__ counters, // [B], pre-zeroed
        float4* __restrict__ out4) {
    __shared__ float4 lds[F4];
    __shared__ unsigned s_old;

    const int tid = threadIdx.x;
    const int f4  = tid & 127;
    const int tg  = tid >> 7;           // 0 or 1
    const int blk = blockIdx.x;
    const int b   = blk >> 5;           // / TSPLIT
    const int ts  = blk & 31;

    // ---- phase 1: partial column sum over this block's 16 rows ----
    const float4* xp = x4 + ((size_t)b * TT + (size_t)ts * TROWS + tg * 8) * F4 + f4;
    float4 a = make_float4(0.f, 0.f, 0.f, 0.f);
#pragma unroll
    for (int t = 0; t < 8; ++t) {
        float4 v = xp[(size_t)t * F4];
        acc4(a, v);
    }
    if (tg == 1) lds[f4] = a;
    __syncthreads();
    if (tg == 0) {
        acc4(a, lds[f4]);
        part4[(size_t)blk * F4 + f4] = a;
    }
    // make partial visible device-wide before bumping the counter
    __threadfence();
    __syncthreads();
    if (tid == 0) s_old = atomicAdd(&counters[b], 1u);
    __syncthreads();
    if (s_old != TSPLIT - 1) return;    // not the last arriver for batch b

    // ---- phase 2 (one block per batch): reduce 32 partials, broadcast ----
    __threadfence();                    // acquire: see other blocks' partials
    const float4* pp = part4 + (size_t)b * TSPLIT * F4 + f4;
    float4 s = make_float4(0.f, 0.f, 0.f, 0.f);
    for (int k = tg; k < TSPLIT; k += 2) {
        float4 v = pp[(size_t)k * F4];
        acc4(s, v);
    }
    if (tg == 1) lds[f4] = s;
    __syncthreads();
    if (tg == 0) {
        acc4(s, lds[f4]);
        lds[f4] = s;
    }
    __syncthreads();
    s = lds[f4];

    float4* op = out4 + (size_t)b * CC * F4 + f4;
    for (int c = tg; c < CC; c += 2) {  // wave -> 1 KB contiguous stores
        op[(size_t)c * F4] = s;
    }
}

extern "C" void kernel_launch(void* const* d_in, const int* in_sizes, int n_in,
                              void* d_out, int out_size, void* d_ws, size_t ws_size,
                              hipStream_t stream) {
    const float* x = (const float*)d_in[0];   // [B,T,F] fp32
    // d_in[1..3] (context, W, b) are dead: softmax over size-1 axis == 1.
    float* out = (float*)d_out;               // [B,C,F] fp32

    // ws layout: [0,128) counters (32 x u32), [256, 256 + 2 MB) partials.
    unsigned* counters = (unsigned*)d_ws;
    float4*   part4    = (float4*)((char*)d_ws + 256);

    hipMemsetAsync(counters, 0, BB * sizeof(unsigned), stream);
    fused_colsum_bcast<<<BB * TSPLIT, 256, 0, stream>>>(
        (const float4*)x, part4, counters, (float4*)out);
}

// Round 3
// 82.475 us; speedup vs baseline: 2.4710x; 2.4710x over previous
//
#include <hip/hip_runtime.h>

// B=32, T=512, C=256, F=512.
// Reference softmax is over a size-1 axis -> att == 1.0 exactly, so
// out[b,c,f] = sum_t x[b,t,f], broadcast over c. context/W/b are dead.
// Pure bandwidth: read 33.5 MB (x) once + write 16.8 MB (out) once.
//
// Round-2 lesson: device-scope __threadfence from 1024 blocks = per-XCD L2
// writeback storm (kernel ran at 200 GB/s). This version has NO cross-block
// communication: split by F-chunks, each block fully owns (b, 64-float slice).

#define BB 32
#define TT 512
#define CC 256
#define FF 512
#define F4 (FF / 4)      // 128 float4 per row
#define FC 8             // f-chunks per batch (64 floats = 16 float4 each)

__device__ __forceinline__ void acc4(float4& a, const float4& v) {
    a.x += v.x; a.y += v.y; a.z += v.z; a.w += v.w;
}

// grid = B * FC = 256 blocks, 512 threads (8 waves/CU, ~1 block/CU).
// tid -> (g = tid>>4 in 0..31 : row group, f4l = tid&15 : float4 column).
__global__ __launch_bounds__(512) void colsum_bcast(const float4* __restrict__ x4,
                                                    float4* __restrict__ out4) {
    __shared__ float4 lds[32][16];      // 8 KB

    const int tid = threadIdx.x;
    const int f4l = tid & 15;
    const int g   = tid >> 4;           // 0..31
    const int b   = blockIdx.x >> 3;    // / FC
    const int fc  = blockIdx.x & 7;

    // ---- read: each thread sums 16 rows (g + 32k) of its float4 column ----
    const float4* xp = x4 + (size_t)b * TT * F4 + fc * 16 + f4l;
    float4 a = make_float4(0.f, 0.f, 0.f, 0.f);
#pragma unroll
    for (int k = 0; k < 16; ++k) {      // 16 independent loads in flight
        float4 v = xp[(size_t)(g + 32 * k) * F4];
        acc4(a, v);
    }
    lds[g][f4l] = a;
    __syncthreads();

    // ---- reduce 32 row-group partials per column (workgroup scope only) ----
    if (tid < 16) {
        float4 s = lds[0][tid];
#pragma unroll
        for (int r = 1; r < 32; ++r) acc4(s, lds[r][tid]);
        lds[0][tid] = s;
    }
    __syncthreads();
    const float4 s = lds[0][f4l];

    // ---- broadcast-store across the 256 c-rows of this (b, f-chunk) ----
    float4* op = out4 + (size_t)b * CC * F4 + fc * 16 + f4l;
#pragma unroll
    for (int k = 0; k < 8; ++k) {
        op[(size_t)(g + 32 * k) * F4] = s;
    }
}

extern "C" void kernel_launch(void* const* d_in, const int* in_sizes, int n_in,
                              void* d_out, int out_size, void* d_ws, size_t ws_size,
                              hipStream_t stream) {
    const float* x = (const float*)d_in[0];   // [B,T,F] fp32
    // d_in[1..3] (context, W, b) are dead: softmax over size-1 axis == 1.
    float* out = (float*)d_out;               // [B,C,F] fp32
    (void)d_ws; (void)ws_size;

    colsum_bcast<<<BB * FC, 512, 0, stream>>>((const float4*)x, (float4*)out);
}